// Round 8
// baseline (75.501 us; speedup 1.0000x reference)
//
#include <hip/hip_runtime.h>
#include <hip/hip_bf16.h>

// LocallyConnected1d: x (64,64,1024) f32, weights (1024,64,64,9) f32, bias (64,1024) f32
// out[b*65536 + w*64 + o] = sum_{c,t} x[b,c,w+t-4] * weights[w,o,c,t] + bias_flat[w*64+o]
// Round 8: SINGLE fused kernel. Per-w GEMM M=64,N=64,K=576. Weight stream (151MB,
// read-once, NT-hinted) = roofline. A-panel staged DIRECTLY from x (no Xt prepass):
// all 1024 blocks co-resident (4/CU), so x first-touches merge in L2 across the 128
// concurrent blocks per XCD (XCD-contiguous w mapping) -> x costs ~17MB HBM, and the
// Xt round-trip (17MB + serial prepass bubble) is eliminated entirely.
// Floor: 151 + 17 + 17 = 185MB @ 6.3TB/s ~= 29.3us.

typedef __bf16 bf16x8 __attribute__((ext_vector_type(8)));
typedef float  f32x4  __attribute__((ext_vector_type(4)));
typedef float  f32x4u __attribute__((ext_vector_type(4), aligned(4)));

#define NK    576
#define LDAP  296                      // 288 + 8 pad (per-phase panel), rows 16B-aligned
#define NCH   18
#define PFD   6

// barrier that does NOT drain vmcnt (keeps weight/x prefetch in flight)
#define LGKM_BAR() asm volatile("s_waitcnt lgkmcnt(0)\n\ts_barrier" ::: "memory")

// Load 9 window taps of one (b,c) row. Interior: 2 unaligned vec4 + 1 scalar.
// Edge (8 blocks): per-tap predicated scalars. `interior`/`w` are wave-uniform.
__device__ __forceinline__ void load_row9(const float* xr, bool interior, int w, float f[9]) {
    if (interior) {
        f32x4 u0 = *reinterpret_cast<const f32x4u*>(xr);
        f32x4 u1 = *reinterpret_cast<const f32x4u*>(xr + 4);
        float s  = xr[8];
        #pragma unroll
        for (int i = 0; i < 4; ++i) { f[i] = u0[i]; f[4 + i] = u1[i]; }
        f[8] = s;
    } else {
        #pragma unroll
        for (int t = 0; t < 9; ++t) {
            int pos = w - 4 + t;
            f[t] = ((unsigned)pos < 1024u) ? xr[t] : 0.f;
        }
    }
}

__global__ __launch_bounds__(256, 4)
void lc1d_kernel(const float* __restrict__ x,
                 const float* __restrict__ wts,
                 const float* __restrict__ bias,
                 float* __restrict__ out) {
    __shared__ __bf16 Alds[64][LDAP];

    // XCD-contiguous w mapping: each XCD gets a contiguous 128-w range; its x
    // working set (~2.2MB) is fetched once (concurrent blocks merge misses).
    const int orig = blockIdx.x;
    const int w    = ((orig & 7) << 7) | (orig >> 3);

    const int tid  = threadIdx.x;
    const int lane = tid & 63;
    const int wv   = tid >> 6;
    const int m16  = lane & 15;
    const int ko   = (lane >> 4) * 8;
    const int o    = wv * 16 + m16;

    const float* wbase = wts + (size_t)w * (64 * NK) + (size_t)o * NK + ko;
    const float bv = bias[w * 64 + o];          // hoisted epilogue bias

    // staging identity: thread -> (row b = sb, c-octet sc within phase)
    const int sb = tid >> 2;
    const int sc = (tid & 3) * 8;
    const bool interior = (w >= 4) && (w <= 1019);
    const float* xrow0 = x + ((size_t)(sb * 64 + sc) << 10) + (w - 4);

    // ================= phase 0 staging =================
    // batch 0 (rows c-local 0..3) — issue x loads FIRST so the later convert's
    // vmcnt wait leaves the weight loads (issued next) in flight.
    float f0[4][9];
    #pragma unroll
    for (int r = 0; r < 4; ++r)
        load_row9(xrow0 + ((size_t)r << 10), interior, w, f0[r]);

    // weight prefetch pipeline (read-once -> nontemporal)
    f32x4 wr0[PFD], wr1[PFD];
    #pragma unroll
    for (int p = 0; p < PFD; ++p) {
        wr0[p] = __builtin_nontemporal_load(reinterpret_cast<const f32x4*>(wbase + p * 32));
        wr1[p] = __builtin_nontemporal_load(reinterpret_cast<const f32x4*>(wbase + p * 32 + 4));
    }

    // convert batch0 -> words 0..3 complete + word4 low half; write words 0..3 now
    bf16x8 Wd[9];
    #pragma unroll
    for (int r = 0; r < 4; ++r)
        #pragma unroll
        for (int t = 0; t < 9; ++t) { int n = r * 9 + t; Wd[n >> 3][n & 7] = (__bf16)f0[r][t]; }
    __bf16* dst = &Alds[sb][sc * 9];
    #pragma unroll
    for (int q = 0; q < 4; ++q) *reinterpret_cast<bf16x8*>(dst + q * 8) = Wd[q];

    // batch 1 (rows c-local 4..7)
    float f1[4][9];
    #pragma unroll
    for (int r = 0; r < 4; ++r)
        load_row9(xrow0 + ((size_t)(4 + r) << 10), interior, w, f1[r]);
    #pragma unroll
    for (int r = 0; r < 4; ++r)
        #pragma unroll
        for (int t = 0; t < 9; ++t) { int n = 36 + r * 9 + t; Wd[n >> 3][n & 7] = (__bf16)f1[r][t]; }
    #pragma unroll
    for (int q = 4; q < 9; ++q) *reinterpret_cast<bf16x8*>(dst + q * 8) = Wd[q];

    LGKM_BAR();

    f32x4 acc[4];
    #pragma unroll
    for (int i = 0; i < 4; ++i) acc[i] = (f32x4){0.f, 0.f, 0.f, 0.f};

    // pre-issue phase-1 batch 0 x loads (rows c-local 32..35); held in regs through
    // phase-0 MFMA — the asm memory clobbers pin issue before / use after the barriers.
    float fp[4][9];
    #pragma unroll
    for (int r = 0; r < 4; ++r)
        load_row9(xrow0 + ((size_t)(32 + r) << 10), interior, w, fp[r]);

    // ================= phase 0 MFMA: chunks 0..8 =================
    #pragma unroll
    for (int it = 0; it < 9; ++it) {
        const int s = it % PFD;
        f32x4 u0 = wr0[s], u1 = wr1[s];
        wr0[s] = __builtin_nontemporal_load(reinterpret_cast<const f32x4*>(wbase + (it + PFD) * 32));
        wr1[s] = __builtin_nontemporal_load(reinterpret_cast<const f32x4*>(wbase + (it + PFD) * 32 + 4));
        bf16x8 bf;
        #pragma unroll
        for (int j = 0; j < 4; ++j) { bf[j] = (__bf16)u0[j]; bf[j + 4] = (__bf16)u1[j]; }
        const int kk0 = it * 32;
        #pragma unroll
        for (int bt = 0; bt < 4; ++bt) {
            bf16x8 af = *reinterpret_cast<const bf16x8*>(&Alds[bt * 16 + m16][kk0 + ko]);
            acc[bt] = __builtin_amdgcn_mfma_f32_16x16x32_bf16(af, bf, acc[bt], 0, 0, 0);
        }
    }

    LGKM_BAR();   // WAR: all waves done reading phase-0 panel

    // ================= phase 1 staging =================
    #pragma unroll
    for (int r = 0; r < 4; ++r)
        #pragma unroll
        for (int t = 0; t < 9; ++t) { int n = r * 9 + t; Wd[n >> 3][n & 7] = (__bf16)fp[r][t]; }
    #pragma unroll
    for (int q = 0; q < 4; ++q) *reinterpret_cast<bf16x8*>(dst + q * 8) = Wd[q];

    float f3[4][9];
    #pragma unroll
    for (int r = 0; r < 4; ++r)
        load_row9(xrow0 + ((size_t)(36 + r) << 10), interior, w, f3[r]);
    #pragma unroll
    for (int r = 0; r < 4; ++r)
        #pragma unroll
        for (int t = 0; t < 9; ++t) { int n = 36 + r * 9 + t; Wd[n >> 3][n & 7] = (__bf16)f3[r][t]; }
    #pragma unroll
    for (int q = 4; q < 9; ++q) *reinterpret_cast<bf16x8*>(dst + q * 8) = Wd[q];

    LGKM_BAR();

    // ================= phase 1 MFMA: chunks 9..17 =================
    #pragma unroll
    for (int it = 9; it < NCH; ++it) {
        const int s = it % PFD;
        f32x4 u0 = wr0[s], u1 = wr1[s];
        if (it + PFD < NCH) {
            wr0[s] = __builtin_nontemporal_load(reinterpret_cast<const f32x4*>(wbase + (it + PFD) * 32));
            wr1[s] = __builtin_nontemporal_load(reinterpret_cast<const f32x4*>(wbase + (it + PFD) * 32 + 4));
        }
        bf16x8 bf;
        #pragma unroll
        for (int j = 0; j < 4; ++j) { bf[j] = (__bf16)u0[j]; bf[j + 4] = (__bf16)u1[j]; }
        const int kk0 = (it - 9) * 32;
        #pragma unroll
        for (int bt = 0; bt < 4; ++bt) {
            bf16x8 af = *reinterpret_cast<const bf16x8*>(&Alds[bt * 16 + m16][kk0 + ko]);
            acc[bt] = __builtin_amdgcn_mfma_f32_16x16x32_bf16(af, bf, acc[bt], 0, 0, 0);
        }
    }

    // ================= epilogue =================
    const int r0 = (lane >> 4) * 4;
    float* outp = out + (size_t)w * 64 + o;
    #pragma unroll
    for (int bt = 0; bt < 4; ++bt) {
        #pragma unroll
        for (int r = 0; r < 4; ++r) {
            int b = bt * 16 + r0 + r;
            outp[(size_t)b * 65536] = acc[bt][r] + bv;
        }
    }
}

extern "C" void kernel_launch(void* const* d_in, const int* in_sizes, int n_in,
                              void* d_out, int out_size, void* d_ws, size_t ws_size,
                              hipStream_t stream) {
    const float* x    = (const float*)d_in[0];
    const float* wts  = (const float*)d_in[1];
    const float* bias = (const float*)d_in[2];
    float* out = (float*)d_out;
    lc1d_kernel<<<dim3(1024), dim3(256), 0, stream>>>(x, wts, bias, out);
}